// Round 9
// baseline (247.083 us; speedup 1.0000x reference)
//
#include <hip/hip_runtime.h>
#include <float.h>
#include <limits.h>

#define MEMN 65536
#define WD 128
#define KSEL 8
#define RD 9
#define BD 32
#define IND 512
#define IFACE 266
#define XI_STRIDE 272   // pad 266 -> 272 floats (1088B, 16B-aligned rows)

#define KSEG 8
#define KSEG_LEN (IND / KSEG)            // 64

#define NCHUNK 64
#define ROWS_PER_CHUNK 1024              // per block; 4 waves x 256 rows
#define CAND_SCAN (NCHUNK * KSEL)        // 512
#define CAND_REAL (CAND_SCAN + RD)       // 521
#define CAND_PER_BATCH 528               // padded

typedef float fvec4 __attribute__((ext_vector_type(4)));

// Sorted ascending (val, idx) top-8 insert; fully unrolled -> registers only.
#define TOP8_INSERT(bv, bi, vin, iin)                                  \
  { float _v = (vin); int _i = (iin);                                  \
    _Pragma("unroll")                                                  \
    for (int _j = 0; _j < 8; ++_j) {                                   \
      bool _b = (_v < bv[_j]) || (_v == bv[_j] && _i < bi[_j]);        \
      float _tv = bv[_j]; int _ti = bi[_j];                            \
      bv[_j] = _b ? _v : _tv;  bi[_j] = _b ? _i : _ti;                 \
      _v = _b ? _tv : _v;      _i = _b ? _ti : _i;                     \
    } }

__device__ __forceinline__ fvec4 ntload(const void* p) {
  return __builtin_nontemporal_load((const fvec4*)p);
}

// Split-K partial GEMM: block (b, seg) computes 64-deep partials for all 266 cols.
__global__ __launch_bounds__(288)
void xi_part_kernel(const float* __restrict__ x, const float* __restrict__ Wif,
                    float* __restrict__ xi_part) {
  const int b = blockIdx.x, seg = blockIdx.y, c = threadIdx.x;
  if (c >= IFACE) return;
  const float* xr = x + b * IND + seg * KSEG_LEN;       // block-uniform -> s_loads
  const float* wp = Wif + (size_t)(seg * KSEG_LEN) * IFACE + c;
  float a0 = 0.f, a1 = 0.f, a2 = 0.f, a3 = 0.f;
  #pragma unroll
  for (int k = 0; k < KSEG_LEN; k += 4) {
    a0 += xr[k]     * wp[(size_t)k * IFACE];
    a1 += xr[k + 1] * wp[(size_t)(k + 1) * IFACE];
    a2 += xr[k + 2] * wp[(size_t)(k + 2) * IFACE];
    a3 += xr[k + 3] * wp[(size_t)(k + 3) * IFACE];
  }
  xi_part[(b * KSEG + seg) * XI_STRIDE + c] = (a0 + a1) + (a2 + a3);
}

// Fused: xi reduce (+bias) -> gates/new_rv -> fixup candidate scores.
__global__ __launch_bounds__(320)
void head_kernel(const float* __restrict__ xi_part, const float* __restrict__ bif,
                 const float* __restrict__ read_weights, const float* __restrict__ read_vectors,
                 const int* __restrict__ rpos,
                 float* __restrict__ xi, float* __restrict__ new_rv,
                 float* __restrict__ cand_val, int* __restrict__ cand_idx) {
  const int b = blockIdx.x, t = threadIdx.x;  // 320
  __shared__ float xiS[IFACE];
  __shared__ float wwS[RD];
  __shared__ float nvS[RD][WD];

  // phase 0: reduce split-K partials
  if (t < IFACE) {
    float acc = bif[t];
    #pragma unroll
    for (int s = 0; s < KSEG; ++s)
      acc += xi_part[(b * KSEG + s) * XI_STRIDE + t];
    xiS[t] = acc;
    xi[b * XI_STRIDE + t] = acc;   // scan reads query cols [0,128)
  }
  __syncthreads();

  // phase 1: write weights
  if (t < RD) {
    float g  = 1.f / (1.f + __expf(-xiS[2 * WD + t]));
    float wg = 1.f / (1.f + __expf(-xiS[IFACE - 1]));
    wwS[t] = wg * (g * read_weights[b * RD + t] + (1.f - g));
  }
  __syncthreads();

  // phase 2: new_rv
  if (t < WD) {
    const float wv = xiS[WD + t];
    #pragma unroll
    for (int r = 0; r < RD; ++r) {
      float nv = read_vectors[(b * RD + r) * WD + t] + wwS[r] * wv;
      nvS[r][t] = nv;
      new_rv[(b * RD + r) * WD + t] = nv;
    }
  }
  __syncthreads();

  // phase 3: fixup scores for the 9 scattered rows (wave 0 only)
  if (t < 64) {
    const int lane = t;
    const float q0 = xiS[lane * 2], q1 = xiS[lane * 2 + 1];
    for (int r = 0; r < RD; ++r) {
      float m0 = nvS[r][lane * 2], m1 = nvS[r][lane * 2 + 1];
      float s = m0 * (m0 - 2.f * q0) + m1 * (m1 - 2.f * q1);
      #pragma unroll
      for (int off = 32; off; off >>= 1) s += __shfl_xor(s, off);
      if (lane == 0) {
        int p = rpos[b * RD + r];
        bool dup = false;
        for (int r2 = r + 1; r2 < RD; ++r2) dup |= (rpos[b * RD + r2] == p);
        int slot = b * CAND_PER_BATCH + CAND_SCAN + r;
        cand_val[slot] = dup ? FLT_MAX : s;   // numpy scatter: last duplicate wins
        cand_idx[slot] = dup ? INT_MAX : p;
      }
    }
  }
}

// 256 threads = 4 waves; wave handles 4 rows/iter via 32-lane groups.
// Lane l reads bytes (l&31)*16 of row (rowbase + (l>>5)): one wave load
// instruction covers 1KiB FULLY CONTIGUOUS (2 adjacent rows) — byte-identical
// addressing to the 6.29 TB/s copy ubench. Continues the measured contiguity
// gradient: 64B(R6)->128B(R7,+13us)->256B(R8,+12us)->512B/row (this).
// nt + unroll-depth held R8-equal (2 loads/iter x unroll 4 = 8 in flight).
__global__ __launch_bounds__(256)
void scan_kernel(const float* __restrict__ memory, const float* __restrict__ xi,
                 const int* __restrict__ rpos,
                 float* __restrict__ cand_val, int* __restrict__ cand_idx) {
  const int b = blockIdx.y, chunk = blockIdx.x;
  const int t = threadIdx.x;
  const int w = t >> 6, l = t & 63, g = l >> 5, ln = l & 31;
  const int waveBase = chunk * ROWS_PER_CHUNK + w * (ROWS_PER_CHUNK / 4);

  int rp[RD];
  #pragma unroll
  for (int r = 0; r < RD; ++r) rp[r] = rpos[b * RD + r];

  // 2*query, this lane's 4 columns: cols ln*4..ln*4+3
  const fvec4 q = *(const fvec4*)(xi + b * XI_STRIDE + ln * 4);
  const fvec4 tq = q * 2.f;

  float bv[8]; int bi[8];
  #pragma unroll
  for (int j = 0; j < 8; ++j) { bv[j] = FLT_MAX; bi[j] = INT_MAX; }

  const char* base = (const char*)memory
                   + ((size_t)b * MEMN + waveBase) * (WD * 4) + (size_t)l * 16;

  #pragma unroll 4
  for (int i = 0; i < ROWS_PER_CHUNK / 4 / 4; ++i) {    // 64 iters, 4 rows each
    const char* p = base + (size_t)i * 2048;
    const fvec4 m0 = ntload(p);           // rows rowb+g
    const fvec4 m1 = ntload(p + 1024);    // rows rowb+2+g

    float s0 = m0.x*(m0.x-tq.x) + m0.y*(m0.y-tq.y)
             + m0.z*(m0.z-tq.z) + m0.w*(m0.w-tq.w);
    float s1 = m1.x*(m1.x-tq.x) + m1.y*(m1.y-tq.y)
             + m1.z*(m1.z-tq.z) + m1.w*(m1.w-tq.w);

    #pragma unroll
    for (int off = 1; off < 32; off <<= 1) {   // 2 interleaved 32-lane reduces
      s0 += __shfl_xor(s0, off);
      s1 += __shfl_xor(s1, off);
    }

    if (ln == 0) {                // lanes 0 (g=0) and 32 (g=1)
      const int m0r = waveBase + i * 4 + g;
      const int m1r = m0r + 2;
      bool k0 = false, k1 = false;
      #pragma unroll
      for (int r = 0; r < RD; ++r) { k0 |= (m0r == rp[r]); k1 |= (m1r == rp[r]); }
      if (!k0 && (s0 < bv[7] || (s0 == bv[7] && m0r < bi[7]))) TOP8_INSERT(bv, bi, s0, m0r);
      if (!k1 && (s1 < bv[7] || (s1 == bv[7] && m1r < bi[7]))) TOP8_INSERT(bv, bi, s1, m1r);
    }
  }

  // Merge 8 group-top8s (4 waves x 2 groups) -> chunk top8.
  __shared__ float lv[8][8];
  __shared__ int   li[8][8];
  if (ln == 0) {
    #pragma unroll
    for (int j = 0; j < 8; ++j) { lv[w * 2 + g][j] = bv[j]; li[w * 2 + g][j] = bi[j]; }
  }
  __syncthreads();
  for (int s = 4; s >= 1; s >>= 1) {
    if (t < s) {
      float mv[8]; int mi[8];
      #pragma unroll
      for (int j = 0; j < 8; ++j) { mv[j] = lv[t][j]; mi[j] = li[t][j]; }
      #pragma unroll
      for (int j = 0; j < 8; ++j) {
        float v = lv[t + s][j]; int i = li[t + s][j];
        if (v < mv[7] || (v == mv[7] && i < mi[7])) TOP8_INSERT(mv, mi, v, i);
      }
      #pragma unroll
      for (int j = 0; j < 8; ++j) { lv[t][j] = mv[j]; li[t][j] = mi[j]; }
    }
    __syncthreads();
  }
  if (t < 8) {
    cand_val[b * CAND_PER_BATCH + chunk * 8 + t] = lv[0][t];
    cand_idx[b * CAND_PER_BATCH + chunk * 8 + t] = li[0][t];
  }
}

__global__ __launch_bounds__(128)
void final_kernel(const float* __restrict__ cand_val, const int* __restrict__ cand_idx,
                  const float* __restrict__ memory, const float* __restrict__ new_rv,
                  const int* __restrict__ rpos, float* __restrict__ out) {
  const int b = blockIdx.x, t = threadIdx.x;  // 128
  __shared__ float lv[128][8];
  __shared__ int   li[128][8];
  __shared__ int   posS[KSEL], srcS[KSEL];

  float bv[8]; int bi[8];
  #pragma unroll
  for (int j = 0; j < 8; ++j) { bv[j] = FLT_MAX; bi[j] = INT_MAX; }

  for (int e = t; e < CAND_REAL; e += 128) {
    float v = cand_val[b * CAND_PER_BATCH + e];
    int   i = cand_idx[b * CAND_PER_BATCH + e];
    if (v < bv[7] || (v == bv[7] && i < bi[7])) TOP8_INSERT(bv, bi, v, i);
  }
  #pragma unroll
  for (int j = 0; j < 8; ++j) { lv[t][j] = bv[j]; li[t][j] = bi[j]; }
  __syncthreads();

  for (int stride = 64; stride >= 1; stride >>= 1) {
    if (t < stride) {
      #pragma unroll
      for (int j = 0; j < 8; ++j) {
        float v = lv[t + stride][j]; int i = li[t + stride][j];
        if (v < bv[7] || (v == bv[7] && i < bi[7])) TOP8_INSERT(bv, bi, v, i);
      }
      #pragma unroll
      for (int j = 0; j < 8; ++j) { lv[t][j] = bv[j]; li[t][j] = bi[j]; }
    }
    __syncthreads();
  }

  if (t < KSEL) {
    int p = li[0][t];
    int src = -1;
    for (int r = 0; r < RD; ++r) if (rpos[b * RD + r] == p) src = r;  // last wins
    posS[t] = p; srcS[t] = src;
  }
  __syncthreads();

  for (int e = t; e < KSEL * WD; e += 128) {
    int k = e >> 7, wv = e & 127;
    int p = posS[k], src = srcS[k];
    float val = (src >= 0) ? new_rv[(b * RD + src) * WD + wv]
                           : memory[((size_t)b * MEMN + p) * WD + wv];
    out[b * KSEL * WD + e] = val;
  }
}

extern "C" void kernel_launch(void* const* d_in, const int* in_sizes, int n_in,
                              void* d_out, int out_size, void* d_ws, size_t ws_size,
                              hipStream_t stream) {
  const float* x      = (const float*)d_in[0];
  const float* Wif    = (const float*)d_in[1];
  const float* bif    = (const float*)d_in[2];
  const float* memory = (const float*)d_in[3];
  const float* rw     = (const float*)d_in[4];
  const float* rv     = (const float*)d_in[5];
  const int*   rpos   = (const int*)d_in[6];
  // d_in[7] (last_used_mem) unused: reference drops that gathered row.

  float* ws       = (float*)d_ws;
  float* xi_part  = ws;                                   // BD*KSEG*XI_STRIDE floats
  float* xi       = xi_part + BD * KSEG * XI_STRIDE;      // BD*XI_STRIDE
  float* new_rv   = xi + BD * XI_STRIDE;                  // BD*RD*WD
  float* cand_val = new_rv + BD * RD * WD;                // BD*CAND_PER_BATCH
  int*   cand_idx = (int*)(cand_val + BD * CAND_PER_BATCH);
  float* out      = (float*)d_out;

  xi_part_kernel<<<dim3(BD, KSEG), dim3(288), 0, stream>>>(x, Wif, xi_part);
  head_kernel<<<dim3(BD), dim3(320), 0, stream>>>(xi_part, bif, rw, rv, rpos,
                                                  xi, new_rv, cand_val, cand_idx);
  scan_kernel<<<dim3(NCHUNK, BD), dim3(256), 0, stream>>>(memory, xi, rpos, cand_val, cand_idx);
  final_kernel<<<dim3(BD), dim3(128), 0, stream>>>(cand_val, cand_idx, memory, new_rv, rpos, out);
}

// Round 10
// 239.298 us; speedup vs baseline: 1.0325x; 1.0325x over previous
//
#include <hip/hip_runtime.h>
#include <float.h>
#include <limits.h>

#define MEMN 65536
#define WD 128
#define KSEL 8
#define RD 9
#define BD 32
#define IND 512
#define IFACE 266
#define XI_STRIDE 272   // pad 266 -> 272 floats (1088B, 16B-aligned rows)

#define KSEG 8
#define KSEG_LEN (IND / KSEG)            // 64

#define NCHUNK 64
#define ROWS_PER_CHUNK 1024              // per block; 4 waves x 256 rows
#define CAND_SCAN (NCHUNK * KSEL)        // 512
#define CAND_REAL (CAND_SCAN + RD)       // 521
#define CAND_PER_BATCH 528               // padded

typedef float fvec4 __attribute__((ext_vector_type(4)));

// Sorted ascending (val, idx) top-8 insert; fully unrolled -> registers only.
#define TOP8_INSERT(bv, bi, vin, iin)                                  \
  { float _v = (vin); int _i = (iin);                                  \
    _Pragma("unroll")                                                  \
    for (int _j = 0; _j < 8; ++_j) {                                   \
      bool _b = (_v < bv[_j]) || (_v == bv[_j] && _i < bi[_j]);        \
      float _tv = bv[_j]; int _ti = bi[_j];                            \
      bv[_j] = _b ? _v : _tv;  bi[_j] = _b ? _i : _ti;                 \
      _v = _b ? _tv : _v;      _i = _b ? _ti : _i;                     \
    } }

// Split-K partial GEMM: block (b, seg) computes 64-deep partials for all 266 cols.
__global__ __launch_bounds__(288)
void xi_part_kernel(const float* __restrict__ x, const float* __restrict__ Wif,
                    float* __restrict__ xi_part) {
  const int b = blockIdx.x, seg = blockIdx.y, c = threadIdx.x;
  if (c >= IFACE) return;
  const float* xr = x + b * IND + seg * KSEG_LEN;       // block-uniform -> s_loads
  const float* wp = Wif + (size_t)(seg * KSEG_LEN) * IFACE + c;
  float a0 = 0.f, a1 = 0.f, a2 = 0.f, a3 = 0.f;
  #pragma unroll
  for (int k = 0; k < KSEG_LEN; k += 4) {
    a0 += xr[k]     * wp[(size_t)k * IFACE];
    a1 += xr[k + 1] * wp[(size_t)(k + 1) * IFACE];
    a2 += xr[k + 2] * wp[(size_t)(k + 2) * IFACE];
    a3 += xr[k + 3] * wp[(size_t)(k + 3) * IFACE];
  }
  xi_part[(b * KSEG + seg) * XI_STRIDE + c] = (a0 + a1) + (a2 + a3);
}

// Fused: xi reduce (+bias) -> gates/new_rv -> fixup candidate scores.
__global__ __launch_bounds__(320)
void head_kernel(const float* __restrict__ xi_part, const float* __restrict__ bif,
                 const float* __restrict__ read_weights, const float* __restrict__ read_vectors,
                 const int* __restrict__ rpos,
                 float* __restrict__ xi, float* __restrict__ new_rv,
                 float* __restrict__ cand_val, int* __restrict__ cand_idx) {
  const int b = blockIdx.x, t = threadIdx.x;  // 320
  __shared__ float xiS[IFACE];
  __shared__ float wwS[RD];
  __shared__ float nvS[RD][WD];

  // phase 0: reduce split-K partials
  if (t < IFACE) {
    float acc = bif[t];
    #pragma unroll
    for (int s = 0; s < KSEG; ++s)
      acc += xi_part[(b * KSEG + s) * XI_STRIDE + t];
    xiS[t] = acc;
    xi[b * XI_STRIDE + t] = acc;   // scan reads query cols [0,128)
  }
  __syncthreads();

  // phase 1: write weights
  if (t < RD) {
    float g  = 1.f / (1.f + __expf(-xiS[2 * WD + t]));
    float wg = 1.f / (1.f + __expf(-xiS[IFACE - 1]));
    wwS[t] = wg * (g * read_weights[b * RD + t] + (1.f - g));
  }
  __syncthreads();

  // phase 2: new_rv
  if (t < WD) {
    const float wv = xiS[WD + t];
    #pragma unroll
    for (int r = 0; r < RD; ++r) {
      float nv = read_vectors[(b * RD + r) * WD + t] + wwS[r] * wv;
      nvS[r][t] = nv;
      new_rv[(b * RD + r) * WD + t] = nv;
    }
  }
  __syncthreads();

  // phase 3: fixup scores for the 9 scattered rows (wave 0 only)
  if (t < 64) {
    const int lane = t;
    const float q0 = xiS[lane * 2], q1 = xiS[lane * 2 + 1];
    for (int r = 0; r < RD; ++r) {
      float m0 = nvS[r][lane * 2], m1 = nvS[r][lane * 2 + 1];
      float s = m0 * (m0 - 2.f * q0) + m1 * (m1 - 2.f * q1);
      #pragma unroll
      for (int off = 32; off; off >>= 1) s += __shfl_xor(s, off);
      if (lane == 0) {
        int p = rpos[b * RD + r];
        bool dup = false;
        for (int r2 = r + 1; r2 < RD; ++r2) dup |= (rpos[b * RD + r2] == p);
        int slot = b * CAND_PER_BATCH + CAND_SCAN + r;
        cand_val[slot] = dup ? FLT_MAX : s;   // numpy scatter: last duplicate wins
        cand_idx[slot] = dup ? INT_MAX : p;
      }
    }
  }
}

// R8 structure (measured optimum): 256 threads = 4 waves; wave handles 4
// rows/iter via 16-lane groups. Lane ln reads bytes ln*16 + j*256 (j=0,1) of
// row (base + i*4 + g): wave iter footprint = 2KB contiguous, reduce = 4
// intra-16-lane xor steps. SINGLE CHANGE vs R8: plain loads instead of
// __builtin_nontemporal_load (A/B the nt flag — last untested memory-path
// knob; R9 falsified further contiguity gains).
__global__ __launch_bounds__(256)
void scan_kernel(const float* __restrict__ memory, const float* __restrict__ xi,
                 const int* __restrict__ rpos,
                 float* __restrict__ cand_val, int* __restrict__ cand_idx) {
  const int b = blockIdx.y, chunk = blockIdx.x;
  const int t = threadIdx.x;
  const int w = t >> 6, l = t & 63, g = l >> 4, ln = l & 15;
  const int waveBase = chunk * ROWS_PER_CHUNK + w * (ROWS_PER_CHUNK / 4);

  int rp[RD];
  #pragma unroll
  for (int r = 0; r < RD; ++r) rp[r] = rpos[b * RD + r];

  // 2*query, this lane's 8 columns (2 vec4s): cols ln*4 + j*64
  fvec4 tq[2];
  #pragma unroll
  for (int j = 0; j < 2; ++j) {
    fvec4 q = *(const fvec4*)(xi + b * XI_STRIDE + j * 64 + ln * 4);
    tq[j] = q * 2.f;
  }

  float bv[8]; int bi[8];
  #pragma unroll
  for (int j = 0; j < 8; ++j) { bv[j] = FLT_MAX; bi[j] = INT_MAX; }

  const char* base = (const char*)memory + (size_t)b * MEMN * (WD * 4)
                   + (size_t)(waveBase + g) * (WD * 4) + ln * 16;

  #pragma unroll 4
  for (int i = 0; i < ROWS_PER_CHUNK / 4 / 4; ++i) {    // 64 iters, 4 rows each
    const char* p = base + (size_t)i * 2048;
    const fvec4 m0 = *(const fvec4*)(p);
    const fvec4 m1 = *(const fvec4*)(p + 256);

    float s = m0.x*(m0.x-tq[0].x) + m0.y*(m0.y-tq[0].y)
            + m0.z*(m0.z-tq[0].z) + m0.w*(m0.w-tq[0].w)
            + m1.x*(m1.x-tq[1].x) + m1.y*(m1.y-tq[1].y)
            + m1.z*(m1.z-tq[1].z) + m1.w*(m1.w-tq[1].w);
    s += __shfl_xor(s, 1);
    s += __shfl_xor(s, 2);
    s += __shfl_xor(s, 4);
    s += __shfl_xor(s, 8);        // lanes ln==0 hold full row score

    if (ln == 0) {                // 4 active lanes, one row each
      const int m = waveBase + i * 4 + g;
      bool skip = false;
      #pragma unroll
      for (int r = 0; r < RD; ++r) skip |= (m == rp[r]);  // scattered rows: stale
      if (!skip && (s < bv[7] || (s == bv[7] && m < bi[7]))) TOP8_INSERT(bv, bi, s, m);
    }
  }

  // Merge 16 group-top8s (4 waves x 4 groups) -> chunk top8.
  __shared__ float lv[16][8];
  __shared__ int   li[16][8];
  if (ln == 0) {
    #pragma unroll
    for (int j = 0; j < 8; ++j) { lv[w * 4 + g][j] = bv[j]; li[w * 4 + g][j] = bi[j]; }
  }
  __syncthreads();
  for (int s = 8; s >= 1; s >>= 1) {
    if (t < s) {
      float mv[8]; int mi[8];
      #pragma unroll
      for (int j = 0; j < 8; ++j) { mv[j] = lv[t][j]; mi[j] = li[t][j]; }
      #pragma unroll
      for (int j = 0; j < 8; ++j) {
        float v = lv[t + s][j]; int i = li[t + s][j];
        if (v < mv[7] || (v == mv[7] && i < mi[7])) TOP8_INSERT(mv, mi, v, i);
      }
      #pragma unroll
      for (int j = 0; j < 8; ++j) { lv[t][j] = mv[j]; li[t][j] = mi[j]; }
    }
    __syncthreads();
  }
  if (t < 8) {
    cand_val[b * CAND_PER_BATCH + chunk * 8 + t] = lv[0][t];
    cand_idx[b * CAND_PER_BATCH + chunk * 8 + t] = li[0][t];
  }
}

__global__ __launch_bounds__(128)
void final_kernel(const float* __restrict__ cand_val, const int* __restrict__ cand_idx,
                  const float* __restrict__ memory, const float* __restrict__ new_rv,
                  const int* __restrict__ rpos, float* __restrict__ out) {
  const int b = blockIdx.x, t = threadIdx.x;  // 128
  __shared__ float lv[128][8];
  __shared__ int   li[128][8];
  __shared__ int   posS[KSEL], srcS[KSEL];

  float bv[8]; int bi[8];
  #pragma unroll
  for (int j = 0; j < 8; ++j) { bv[j] = FLT_MAX; bi[j] = INT_MAX; }

  for (int e = t; e < CAND_REAL; e += 128) {
    float v = cand_val[b * CAND_PER_BATCH + e];
    int   i = cand_idx[b * CAND_PER_BATCH + e];
    if (v < bv[7] || (v == bv[7] && i < bi[7])) TOP8_INSERT(bv, bi, v, i);
  }
  #pragma unroll
  for (int j = 0; j < 8; ++j) { lv[t][j] = bv[j]; li[t][j] = bi[j]; }
  __syncthreads();

  for (int stride = 64; stride >= 1; stride >>= 1) {
    if (t < stride) {
      #pragma unroll
      for (int j = 0; j < 8; ++j) {
        float v = lv[t + stride][j]; int i = li[t + stride][j];
        if (v < bv[7] || (v == bv[7] && i < bi[7])) TOP8_INSERT(bv, bi, v, i);
      }
      #pragma unroll
      for (int j = 0; j < 8; ++j) { lv[t][j] = bv[j]; li[t][j] = bi[j]; }
    }
    __syncthreads();
  }

  if (t < KSEL) {
    int p = li[0][t];
    int src = -1;
    for (int r = 0; r < RD; ++r) if (rpos[b * RD + r] == p) src = r;  // last wins
    posS[t] = p; srcS[t] = src;
  }
  __syncthreads();

  for (int e = t; e < KSEL * WD; e += 128) {
    int k = e >> 7, wv = e & 127;
    int p = posS[k], src = srcS[k];
    float val = (src >= 0) ? new_rv[(b * RD + src) * WD + wv]
                           : memory[((size_t)b * MEMN + p) * WD + wv];
    out[b * KSEL * WD + e] = val;
  }
}

extern "C" void kernel_launch(void* const* d_in, const int* in_sizes, int n_in,
                              void* d_out, int out_size, void* d_ws, size_t ws_size,
                              hipStream_t stream) {
  const float* x      = (const float*)d_in[0];
  const float* Wif    = (const float*)d_in[1];
  const float* bif    = (const float*)d_in[2];
  const float* memory = (const float*)d_in[3];
  const float* rw     = (const float*)d_in[4];
  const float* rv     = (const float*)d_in[5];
  const int*   rpos   = (const int*)d_in[6];
  // d_in[7] (last_used_mem) unused: reference drops that gathered row.

  float* ws       = (float*)d_ws;
  float* xi_part  = ws;                                   // BD*KSEG*XI_STRIDE floats
  float* xi       = xi_part + BD * KSEG * XI_STRIDE;      // BD*XI_STRIDE
  float* new_rv   = xi + BD * XI_STRIDE;                  // BD*RD*WD
  float* cand_val = new_rv + BD * RD * WD;                // BD*CAND_PER_BATCH
  int*   cand_idx = (int*)(cand_val + BD * CAND_PER_BATCH);
  float* out      = (float*)d_out;

  xi_part_kernel<<<dim3(BD, KSEG), dim3(288), 0, stream>>>(x, Wif, xi_part);
  head_kernel<<<dim3(BD), dim3(320), 0, stream>>>(xi_part, bif, rw, rv, rpos,
                                                  xi, new_rv, cand_val, cand_idx);
  scan_kernel<<<dim3(NCHUNK, BD), dim3(256), 0, stream>>>(memory, xi, rpos, cand_val, cand_idx);
  final_kernel<<<dim3(BD), dim3(128), 0, stream>>>(cand_val, cand_idx, memory, new_rv, rpos, out);
}

// Round 11
// 215.440 us; speedup vs baseline: 1.1469x; 1.1107x over previous
//
#include <hip/hip_runtime.h>
#include <float.h>
#include <limits.h>

#define MEMN 65536
#define WD 128
#define KSEL 8
#define RD 9
#define BD 32
#define IND 512
#define IFACE 266
#define XI_STRIDE 272   // pad 266 -> 272 floats (1088B, 16B-aligned rows)

#define KSEG 8
#define KSEG_LEN (IND / KSEG)            // 64

#define NCHUNK 64
#define ROWS_PER_CHUNK 1024              // per block; 4 waves x 256 rows
#define CAND_SCAN (NCHUNK * KSEL)        // 512
#define CAND_REAL (CAND_SCAN + RD)       // 521
#define CAND_PER_BATCH 528               // padded

typedef float fvec4 __attribute__((ext_vector_type(4)));

// Sorted ascending (val, idx) top-8 insert; fully unrolled -> registers only.
#define TOP8_INSERT(bv, bi, vin, iin)                                  \
  { float _v = (vin); int _i = (iin);                                  \
    _Pragma("unroll")                                                  \
    for (int _j = 0; _j < 8; ++_j) {                                   \
      bool _b = (_v < bv[_j]) || (_v == bv[_j] && _i < bi[_j]);        \
      float _tv = bv[_j]; int _ti = bi[_j];                            \
      bv[_j] = _b ? _v : _tv;  bi[_j] = _b ? _i : _ti;                 \
      _v = _b ? _tv : _v;      _i = _b ? _ti : _i;                     \
    } }

__device__ __forceinline__ fvec4 ntload(const void* p) {
  return __builtin_nontemporal_load((const fvec4*)p);
}

// Split-K partial GEMM: block (b, seg) computes 64-deep partials for all 266 cols.
__global__ __launch_bounds__(288)
void xi_part_kernel(const float* __restrict__ x, const float* __restrict__ Wif,
                    float* __restrict__ xi_part) {
  const int b = blockIdx.x, seg = blockIdx.y, c = threadIdx.x;
  if (c >= IFACE) return;
  const float* xr = x + b * IND + seg * KSEG_LEN;       // block-uniform -> s_loads
  const float* wp = Wif + (size_t)(seg * KSEG_LEN) * IFACE + c;
  float a0 = 0.f, a1 = 0.f, a2 = 0.f, a3 = 0.f;
  #pragma unroll
  for (int k = 0; k < KSEG_LEN; k += 4) {
    a0 += xr[k]     * wp[(size_t)k * IFACE];
    a1 += xr[k + 1] * wp[(size_t)(k + 1) * IFACE];
    a2 += xr[k + 2] * wp[(size_t)(k + 2) * IFACE];
    a3 += xr[k + 3] * wp[(size_t)(k + 3) * IFACE];
  }
  xi_part[(b * KSEG + seg) * XI_STRIDE + c] = (a0 + a1) + (a2 + a3);
}

// Fused: xi reduce (+bias) -> gates/new_rv -> fixup candidate scores.
__global__ __launch_bounds__(320)
void head_kernel(const float* __restrict__ xi_part, const float* __restrict__ bif,
                 const float* __restrict__ read_weights, const float* __restrict__ read_vectors,
                 const int* __restrict__ rpos,
                 float* __restrict__ xi, float* __restrict__ new_rv,
                 float* __restrict__ cand_val, int* __restrict__ cand_idx) {
  const int b = blockIdx.x, t = threadIdx.x;  // 320
  __shared__ float xiS[IFACE];
  __shared__ float wwS[RD];
  __shared__ float nvS[RD][WD];

  // phase 0: reduce split-K partials
  if (t < IFACE) {
    float acc = bif[t];
    #pragma unroll
    for (int s = 0; s < KSEG; ++s)
      acc += xi_part[(b * KSEG + s) * XI_STRIDE + t];
    xiS[t] = acc;
    xi[b * XI_STRIDE + t] = acc;   // scan reads query cols [0,128)
  }
  __syncthreads();

  // phase 1: write weights
  if (t < RD) {
    float g  = 1.f / (1.f + __expf(-xiS[2 * WD + t]));
    float wg = 1.f / (1.f + __expf(-xiS[IFACE - 1]));
    wwS[t] = wg * (g * read_weights[b * RD + t] + (1.f - g));
  }
  __syncthreads();

  // phase 2: new_rv
  if (t < WD) {
    const float wv = xiS[WD + t];
    #pragma unroll
    for (int r = 0; r < RD; ++r) {
      float nv = read_vectors[(b * RD + r) * WD + t] + wwS[r] * wv;
      nvS[r][t] = nv;
      new_rv[(b * RD + r) * WD + t] = nv;
    }
  }
  __syncthreads();

  // phase 3: fixup scores for the 9 scattered rows (wave 0 only)
  if (t < 64) {
    const int lane = t;
    const float q0 = xiS[lane * 2], q1 = xiS[lane * 2 + 1];
    for (int r = 0; r < RD; ++r) {
      float m0 = nvS[r][lane * 2], m1 = nvS[r][lane * 2 + 1];
      float s = m0 * (m0 - 2.f * q0) + m1 * (m1 - 2.f * q1);
      #pragma unroll
      for (int off = 32; off; off >>= 1) s += __shfl_xor(s, off);
      if (lane == 0) {
        int p = rpos[b * RD + r];
        bool dup = false;
        for (int r2 = r + 1; r2 < RD; ++r2) dup |= (rpos[b * RD + r2] == p);
        int slot = b * CAND_PER_BATCH + CAND_SCAN + r;
        cand_val[slot] = dup ? FLT_MAX : s;   // numpy scatter: last duplicate wins
        cand_idx[slot] = dup ? INT_MAX : p;
      }
    }
  }
}

// R8 structure (measured optimum of the family): 256 threads = 4 waves; wave
// handles 4 rows/iter via 16-lane groups; lane ln reads bytes ln*16 + j*256
// (j=0,1) of row (base + i*4 + g); nt loads (R10 proved +24us). SINGLE CHANGE
// vs R8: #pragma unroll 4 -> 8 (8 -> 16 nt loads in flight per lane) to test
// whether the half-density strided instructions need deeper MLP to saturate
// DRAM. All else byte-identical to the 215.6us R8 kernel.
__global__ __launch_bounds__(256)
void scan_kernel(const float* __restrict__ memory, const float* __restrict__ xi,
                 const int* __restrict__ rpos,
                 float* __restrict__ cand_val, int* __restrict__ cand_idx) {
  const int b = blockIdx.y, chunk = blockIdx.x;
  const int t = threadIdx.x;
  const int w = t >> 6, l = t & 63, g = l >> 4, ln = l & 15;
  const int waveBase = chunk * ROWS_PER_CHUNK + w * (ROWS_PER_CHUNK / 4);

  int rp[RD];
  #pragma unroll
  for (int r = 0; r < RD; ++r) rp[r] = rpos[b * RD + r];

  // 2*query, this lane's 8 columns (2 vec4s): cols ln*4 + j*64
  fvec4 tq[2];
  #pragma unroll
  for (int j = 0; j < 2; ++j) {
    fvec4 q = *(const fvec4*)(xi + b * XI_STRIDE + j * 64 + ln * 4);
    tq[j] = q * 2.f;
  }

  float bv[8]; int bi[8];
  #pragma unroll
  for (int j = 0; j < 8; ++j) { bv[j] = FLT_MAX; bi[j] = INT_MAX; }

  const char* base = (const char*)memory + (size_t)b * MEMN * (WD * 4)
                   + (size_t)(waveBase + g) * (WD * 4) + ln * 16;

  #pragma unroll 8
  for (int i = 0; i < ROWS_PER_CHUNK / 4 / 4; ++i) {    // 64 iters, 4 rows each
    const char* p = base + (size_t)i * 2048;
    const fvec4 m0 = ntload(p);
    const fvec4 m1 = ntload(p + 256);

    float s = m0.x*(m0.x-tq[0].x) + m0.y*(m0.y-tq[0].y)
            + m0.z*(m0.z-tq[0].z) + m0.w*(m0.w-tq[0].w)
            + m1.x*(m1.x-tq[1].x) + m1.y*(m1.y-tq[1].y)
            + m1.z*(m1.z-tq[1].z) + m1.w*(m1.w-tq[1].w);
    s += __shfl_xor(s, 1);
    s += __shfl_xor(s, 2);
    s += __shfl_xor(s, 4);
    s += __shfl_xor(s, 8);        // lanes ln==0 hold full row score

    if (ln == 0) {                // 4 active lanes, one row each
      const int m = waveBase + i * 4 + g;
      bool skip = false;
      #pragma unroll
      for (int r = 0; r < RD; ++r) skip |= (m == rp[r]);  // scattered rows: stale
      if (!skip && (s < bv[7] || (s == bv[7] && m < bi[7]))) TOP8_INSERT(bv, bi, s, m);
    }
  }

  // Merge 16 group-top8s (4 waves x 4 groups) -> chunk top8.
  __shared__ float lv[16][8];
  __shared__ int   li[16][8];
  if (ln == 0) {
    #pragma unroll
    for (int j = 0; j < 8; ++j) { lv[w * 4 + g][j] = bv[j]; li[w * 4 + g][j] = bi[j]; }
  }
  __syncthreads();
  for (int s = 8; s >= 1; s >>= 1) {
    if (t < s) {
      float mv[8]; int mi[8];
      #pragma unroll
      for (int j = 0; j < 8; ++j) { mv[j] = lv[t][j]; mi[j] = li[t][j]; }
      #pragma unroll
      for (int j = 0; j < 8; ++j) {
        float v = lv[t + s][j]; int i = li[t + s][j];
        if (v < mv[7] || (v == mv[7] && i < mi[7])) TOP8_INSERT(mv, mi, v, i);
      }
      #pragma unroll
      for (int j = 0; j < 8; ++j) { lv[t][j] = mv[j]; li[t][j] = mi[j]; }
    }
    __syncthreads();
  }
  if (t < 8) {
    cand_val[b * CAND_PER_BATCH + chunk * 8 + t] = lv[0][t];
    cand_idx[b * CAND_PER_BATCH + chunk * 8 + t] = li[0][t];
  }
}

__global__ __launch_bounds__(128)
void final_kernel(const float* __restrict__ cand_val, const int* __restrict__ cand_idx,
                  const float* __restrict__ memory, const float* __restrict__ new_rv,
                  const int* __restrict__ rpos, float* __restrict__ out) {
  const int b = blockIdx.x, t = threadIdx.x;  // 128
  __shared__ float lv[128][8];
  __shared__ int   li[128][8];
  __shared__ int   posS[KSEL], srcS[KSEL];

  float bv[8]; int bi[8];
  #pragma unroll
  for (int j = 0; j < 8; ++j) { bv[j] = FLT_MAX; bi[j] = INT_MAX; }

  for (int e = t; e < CAND_REAL; e += 128) {
    float v = cand_val[b * CAND_PER_BATCH + e];
    int   i = cand_idx[b * CAND_PER_BATCH + e];
    if (v < bv[7] || (v == bv[7] && i < bi[7])) TOP8_INSERT(bv, bi, v, i);
  }
  #pragma unroll
  for (int j = 0; j < 8; ++j) { lv[t][j] = bv[j]; li[t][j] = bi[j]; }
  __syncthreads();

  for (int stride = 64; stride >= 1; stride >>= 1) {
    if (t < stride) {
      #pragma unroll
      for (int j = 0; j < 8; ++j) {
        float v = lv[t + stride][j]; int i = li[t + stride][j];
        if (v < bv[7] || (v == bv[7] && i < bi[7])) TOP8_INSERT(bv, bi, v, i);
      }
      #pragma unroll
      for (int j = 0; j < 8; ++j) { lv[t][j] = bv[j]; li[t][j] = bi[j]; }
    }
    __syncthreads();
  }

  if (t < KSEL) {
    int p = li[0][t];
    int src = -1;
    for (int r = 0; r < RD; ++r) if (rpos[b * RD + r] == p) src = r;  // last wins
    posS[t] = p; srcS[t] = src;
  }
  __syncthreads();

  for (int e = t; e < KSEL * WD; e += 128) {
    int k = e >> 7, wv = e & 127;
    int p = posS[k], src = srcS[k];
    float val = (src >= 0) ? new_rv[(b * RD + src) * WD + wv]
                           : memory[((size_t)b * MEMN + p) * WD + wv];
    out[b * KSEL * WD + e] = val;
  }
}

extern "C" void kernel_launch(void* const* d_in, const int* in_sizes, int n_in,
                              void* d_out, int out_size, void* d_ws, size_t ws_size,
                              hipStream_t stream) {
  const float* x      = (const float*)d_in[0];
  const float* Wif    = (const float*)d_in[1];
  const float* bif    = (const float*)d_in[2];
  const float* memory = (const float*)d_in[3];
  const float* rw     = (const float*)d_in[4];
  const float* rv     = (const float*)d_in[5];
  const int*   rpos   = (const int*)d_in[6];
  // d_in[7] (last_used_mem) unused: reference drops that gathered row.

  float* ws       = (float*)d_ws;
  float* xi_part  = ws;                                   // BD*KSEG*XI_STRIDE floats
  float* xi       = xi_part + BD * KSEG * XI_STRIDE;      // BD*XI_STRIDE
  float* new_rv   = xi + BD * XI_STRIDE;                  // BD*RD*WD
  float* cand_val = new_rv + BD * RD * WD;                // BD*CAND_PER_BATCH
  int*   cand_idx = (int*)(cand_val + BD * CAND_PER_BATCH);
  float* out      = (float*)d_out;

  xi_part_kernel<<<dim3(BD, KSEG), dim3(288), 0, stream>>>(x, Wif, xi_part);
  head_kernel<<<dim3(BD), dim3(320), 0, stream>>>(xi_part, bif, rw, rv, rpos,
                                                  xi, new_rv, cand_val, cand_idx);
  scan_kernel<<<dim3(NCHUNK, BD), dim3(256), 0, stream>>>(memory, xi, rpos, cand_val, cand_idx);
  final_kernel<<<dim3(BD), dim3(128), 0, stream>>>(cand_val, cand_idx, memory, new_rv, rpos, out);
}